// Round 5
// baseline (531.417 us; speedup 1.0000x reference)
//
#include <hip/hip_runtime.h>
#include <hip/hip_bf16.h>
#include <stdint.h>

#define N_NODES 100000
#define N_EDGES 1200000
#define IN_CH 64
#define HID 16
#define OUT_CH 64

#define BSH 7                 // nodes-per-bucket shift
#define BN  (1 << BSH)        // 128 nodes per bucket
#define NB  782               // ceil(100000/128)

typedef __hip_bfloat16 bf16;

__device__ __forceinline__ float b2f(bf16 v) { return __bfloat162float(v); }
__device__ __forceinline__ float lo_f(uint32_t p) { return __uint_as_float(p << 16); }
__device__ __forceinline__ float hi_f(uint32_t p) { return __uint_as_float(p & 0xffff0000u); }

__device__ __forceinline__ float loadf(const void* p, size_t i, int bf) {
    return bf ? b2f(((const bf16*)p)[i]) : ((const float*)p)[i];
}
__device__ __forceinline__ int loadi(const int* p, size_t i, int i64) {
    return i64 ? p[2 * i] : p[i];
}

// Detect dtypes; fold layer-1 edge projection through W1l.
// wc[0..47] = W1e @ W1l (3x16), wc[48..63] = b1e @ W1l
__global__ void k_prep(const void* __restrict__ x, const int* __restrict__ ei,
                       const void* __restrict__ W1e, const void* __restrict__ b1e,
                       const void* __restrict__ W1l, float* __restrict__ wc,
                       int* __restrict__ flags) {
    __shared__ int s_bf;
    if (threadIdx.x == 0) {
        const uint16_t* u = (const uint16_t*)x;
        int cnt = 0;
        for (int i = 0; i < 64; ++i) {
            int e = (u[i] >> 7) & 0xff;
            cnt += (e >= 100 && e <= 140);
        }
        int bf = (cnt >= 50);
        const uint32_t* w = (const uint32_t*)ei;
        int z = 0;
        for (int i = 1; i < 64; i += 2) z += (w[i] == 0u);
        flags[0] = bf;
        flags[1] = (z >= 16);
        s_bf = bf;
    }
    __syncthreads();
    int bf = s_bf;
    int j = threadIdx.x;
    if (j >= HID) return;
    for (int r = 0; r < 3; ++r) {
        float s = 0.f;
        for (int k = 0; k < IN_CH; ++k)
            s += loadf(W1e, r * IN_CH + k, bf) * loadf(W1l, k * HID + j, bf);
        wc[r * HID + j] = s;
    }
    float s = 0.f;
    for (int k = 0; k < IN_CH; ++k)
        s += loadf(b1e, k, bf) * loadf(W1l, k * HID + j, bf);
    wc[3 * HID + j] = s;
}

// y = x@W1l -> y (bf16); z = x@W1r + b1l + b1r -> zh (bf16). 32 threads/row.
__global__ void __launch_bounds__(256) k_y(const void* __restrict__ x,
                                           const void* __restrict__ W1l,
                                           const void* __restrict__ W1r,
                                           const void* __restrict__ b1l,
                                           const void* __restrict__ b1r,
                                           const int* __restrict__ flags,
                                           bf16* __restrict__ y,
                                           bf16* __restrict__ zh) {
    __shared__ float w[IN_CH * 32];  // w[k*32+cc]: cc<16 W1l, cc>=16 W1r
    __shared__ float bz[HID];
    int bf = flags[0];
    for (int t = threadIdx.x; t < IN_CH * 32; t += 256) {
        int k = t >> 5, cc = t & 31;
        w[t] = (cc < 16) ? loadf(W1l, k * HID + cc, bf) : loadf(W1r, k * HID + (cc - 16), bf);
    }
    if (threadIdx.x < HID)
        bz[threadIdx.x] = loadf(b1l, threadIdx.x, bf) + loadf(b1r, threadIdx.x, bf);
    __syncthreads();
    int tid = blockIdx.x * 256 + threadIdx.x;
    int row = tid >> 5;
    if (row >= N_NODES) return;
    int cc = tid & 31;
    float acc = 0.f;
    if (bf) {
        const uint32_t* xr = (const uint32_t*)x + (size_t)row * (IN_CH / 2);
#pragma unroll
        for (int k2 = 0; k2 < IN_CH / 2; ++k2) {
            uint32_t p = xr[k2];
            acc += lo_f(p) * w[(2 * k2) * 32 + cc] + hi_f(p) * w[(2 * k2 + 1) * 32 + cc];
        }
    } else {
        const float* xr = (const float*)x + (size_t)row * IN_CH;
#pragma unroll
        for (int k = 0; k < IN_CH; ++k) acc += xr[k] * w[k * 32 + cc];
    }
    if (cc < 16)
        y[(size_t)row * HID + cc] = __float2bfloat16(acc);
    else
        zh[(size_t)row * HID + (cc - 16)] = __float2bfloat16(acc + bz[cc - 16]);
}

// Bucket histogram (LDS-first).
__global__ void __launch_bounds__(256) k_bhist(const int* __restrict__ ei,
                                               const int* __restrict__ flags,
                                               int* __restrict__ bcount) {
    __shared__ int lh[NB];
    for (int t = threadIdx.x; t < NB; t += 256) lh[t] = 0;
    __syncthreads();
    int i64 = flags[1];
    int stride = gridDim.x * 256;
    for (int e = blockIdx.x * 256 + threadIdx.x; e < N_EDGES; e += stride) {
        int dst = loadi(ei, (size_t)N_EDGES + e, i64);
        atomicAdd(&lh[dst >> BSH], 1);
    }
    __syncthreads();
    for (int t = threadIdx.x; t < NB; t += 256)
        if (lh[t]) atomicAdd(&bcount[t], lh[t]);
}

// Exclusive scan of bucket counts -> boff[0..NB], cursor copy.
__global__ void __launch_bounds__(1024) k_bscan(const int* __restrict__ bcount,
                                                int* __restrict__ boff,
                                                int* __restrict__ cursor) {
    __shared__ int s[1024];
    int t = threadIdx.x;
    int own = (t < NB) ? bcount[t] : 0;
    s[t] = own;
    __syncthreads();
    for (int off = 1; off < 1024; off <<= 1) {
        int v = (t >= off) ? s[t - off] : 0;
        __syncthreads();
        s[t] += v;
        __syncthreads();
    }
    if (t < NB) {
        int ex = s[t] - own;
        boff[t] = ex;
        cursor[t] = ex;
        if (t == NB - 1) boff[NB] = s[t];
    }
}

// Coarse counting-sort scatter: slots[.] = {src, dl<<21 | eid}, grouped by bucket.
#define SC_EPB 4096  // edges per block
__global__ void __launch_bounds__(512) k_bscatter(const int* __restrict__ ei,
                                                  const int* __restrict__ flags,
                                                  int* __restrict__ cursor,
                                                  uint2* __restrict__ slots) {
    __shared__ int lhist[NB];
    __shared__ int lbase[NB];
    for (int t = threadIdx.x; t < NB; t += 512) lhist[t] = 0;
    __syncthreads();
    int i64 = flags[1];
    int base_e = blockIdx.x * SC_EPB;
    uint32_t srcv[8], pack[8], bkt[8], rnk[8];
#pragma unroll
    for (int i = 0; i < 8; ++i) {
        int e = base_e + i * 512 + threadIdx.x;
        bkt[i] = 0xFFFFFFFFu;
        if (e < N_EDGES) {
            int s = loadi(ei, e, i64);
            int d = loadi(ei, (size_t)N_EDGES + e, i64);
            int b = d >> BSH;
            int dl = d & (BN - 1);
            srcv[i] = (uint32_t)s;
            pack[i] = ((uint32_t)dl << 21) | (uint32_t)e;
            bkt[i] = (uint32_t)b;
            rnk[i] = (uint32_t)atomicAdd(&lhist[b], 1);
        }
    }
    __syncthreads();
    for (int b = threadIdx.x; b < NB; b += 512)
        if (lhist[b]) lbase[b] = atomicAdd(&cursor[b], lhist[b]);
    __syncthreads();
#pragma unroll
    for (int i = 0; i < 8; ++i) {
        if (bkt[i] != 0xFFFFFFFFu)
            slots[(size_t)lbase[bkt[i]] + rnk[i]] = make_uint2(srcv[i], pack[i]);
    }
}

// Aggregation layer 1: one block per bucket. LDS-accumulate y[src], ea, deg;
// epilogue computes h = relu(mean-path + z) in place over zh, stores sa/deg.
__global__ void __launch_bounds__(512) k_agg1(const uint2* __restrict__ slots,
                                              const int* __restrict__ boff,
                                              const bf16* __restrict__ y,
                                              const void* __restrict__ ea,
                                              const float* __restrict__ wc,
                                              const int* __restrict__ flags,
                                              bf16* __restrict__ zh,
                                              float* __restrict__ sa,
                                              int* __restrict__ deg_i) {
    __shared__ float facc[BN * HID];   // 8 KB
    __shared__ float sattr[BN * 3];
    __shared__ int   sdeg[BN];
    __shared__ float swc[64];
    int t = threadIdx.x;
    for (int i = t; i < BN * HID; i += 512) facc[i] = 0.f;
    for (int i = t; i < BN * 3; i += 512) sattr[i] = 0.f;
    for (int i = t; i < BN; i += 512) sdeg[i] = 0;
    if (t < 64) swc[t] = wc[t];
    __syncthreads();
    int bf = flags[0];
    int b = blockIdx.x;
    int e0 = boff[b], e1 = boff[b + 1];
    int g = t >> 4, c = t & 15;
    for (int e = e0 + g; e < e1; e += 32) {
        uint2 sl = slots[e];
        int src = (int)sl.x;
        int dl = (int)(sl.y >> 21);
        int eid = (int)(sl.y & 0x1FFFFFu);
        atomicAdd(&facc[dl * HID + c], b2f(y[(size_t)src * HID + c]));
        if (c < 3)
            atomicAdd(&sattr[dl * 3 + c], loadf(ea, (size_t)eid * 3 + c, bf));
        else if (c == 3)
            atomicAdd(&sdeg[dl], 1);
    }
    __syncthreads();
    for (int idx = t; idx < BN * HID; idx += 512) {
        int dl = idx >> 4, cc = idx & 15;
        int i = b * BN + dl;
        if (i >= N_NODES) continue;
        float d = (float)sdeg[dl];
        float inv = 1.0f / fmaxf(d, 1.0f);
        float s0 = sattr[dl * 3 + 0], s1 = sattr[dl * 3 + 1], s2 = sattr[dl * 3 + 2];
        float tt = (facc[idx] + s0 * swc[cc] + s1 * swc[16 + cc] + s2 * swc[32 + cc] +
                    d * swc[48 + cc]) * inv;
        float h = fmaxf(tt + b2f(zh[(size_t)i * HID + cc]), 0.0f);
        zh[(size_t)i * HID + cc] = __float2bfloat16(h);
        if (cc < 3) sa[i * 3 + cc] = sattr[dl * 3 + cc];
        else if (cc == 3) deg_i[i] = sdeg[dl];
    }
}

// Aggregation layer 2 + output epilogue: one block per bucket.
__global__ void __launch_bounds__(512) k_agg2(const uint2* __restrict__ slots,
                                              const int* __restrict__ boff,
                                              const bf16* __restrict__ zh,  // holds h
                                              const float* __restrict__ sa,
                                              const int* __restrict__ deg_i,
                                              const void* __restrict__ W2l,
                                              const void* __restrict__ b2l,
                                              const void* __restrict__ W2r,
                                              const void* __restrict__ b2r,
                                              const void* __restrict__ W2e,
                                              const void* __restrict__ b2e,
                                              const int* __restrict__ flags,
                                              void* __restrict__ out) {
    __shared__ float facc[BN * HID];   // 8 KB (sh, then mean-path term)
    __shared__ float hl[BN * HID];     // 8 KB (h local)
    __shared__ float w2l[HID * OUT_CH];
    __shared__ float w2r[HID * OUT_CH];
    __shared__ float swe[3 * HID];
    __shared__ float sbe[HID];
    __shared__ float sbb[OUT_CH];
    int t = threadIdx.x;
    int bf = flags[0];
    for (int i = t; i < BN * HID; i += 512) facc[i] = 0.f;
    for (int i = t; i < HID * OUT_CH; i += 512) {
        w2l[i] = loadf(W2l, i, bf);
        w2r[i] = loadf(W2r, i, bf);
    }
    if (t < 3 * HID) swe[t] = loadf(W2e, t, bf);
    if (t < HID) sbe[t] = loadf(b2e, t, bf);
    if (t < OUT_CH) sbb[t] = loadf(b2l, t, bf) + loadf(b2r, t, bf);
    __syncthreads();
    int b = blockIdx.x;
    int e0 = boff[b], e1 = boff[b + 1];
    int g = t >> 4, c = t & 15;
    for (int e = e0 + g; e < e1; e += 32) {
        uint2 sl = slots[e];
        int src = (int)sl.x;
        int dl = (int)(sl.y >> 21);
        atomicAdd(&facc[dl * HID + c], b2f(zh[(size_t)src * HID + c]));
    }
    __syncthreads();
    // E1: facc <- mean path term; hl <- h
    for (int idx = t; idx < BN * HID; idx += 512) {
        int dl = idx >> 4, cc = idx & 15;
        int i = b * BN + dl;
        if (i >= N_NODES) { facc[idx] = 0.f; hl[idx] = 0.f; continue; }
        float d = (float)deg_i[i];
        float inv = 1.0f / fmaxf(d, 1.0f);
        float s0 = sa[i * 3 + 0], s1 = sa[i * 3 + 1], s2 = sa[i * 3 + 2];
        facc[idx] = (facc[idx] + s0 * swe[cc] + s1 * swe[16 + cc] + s2 * swe[32 + cc] +
                     d * sbe[cc]) * inv;
        hl[idx] = b2f(zh[(size_t)i * HID + cc]);
    }
    __syncthreads();
    // E2: out[i][j]
    for (int idx = t; idx < BN * OUT_CH; idx += 512) {
        int dl = idx >> 6, j = idx & 63;
        int i = b * BN + dl;
        if (i >= N_NODES) continue;
        float o = sbb[j];
#pragma unroll
        for (int cc = 0; cc < HID; ++cc)
            o += facc[dl * HID + cc] * w2l[cc * OUT_CH + j] +
                 hl[dl * HID + cc] * w2r[cc * OUT_CH + j];
        if (bf)
            ((bf16*)out)[(size_t)i * OUT_CH + j] = __float2bfloat16(o);
        else
            ((float*)out)[(size_t)i * OUT_CH + j] = o;
    }
}

extern "C" void kernel_launch(void* const* d_in, const int* in_sizes, int n_in,
                              void* d_out, int out_size, void* d_ws, size_t ws_size,
                              hipStream_t stream) {
    const void* x   = d_in[0];
    const int*  ei  = (const int*)d_in[1];
    const void* ea  = d_in[2];
    const void* W1l = d_in[3];
    const void* b1l = d_in[4];
    const void* W1r = d_in[5];
    const void* b1r = d_in[6];
    const void* W1e = d_in[7];
    const void* b1e = d_in[8];
    const void* W2l = d_in[9];
    const void* b2l = d_in[10];
    const void* W2r = d_in[11];
    const void* b2r = d_in[12];
    const void* W2e = d_in[13];
    const void* b2e = d_in[14];

    const size_t N16 = (size_t)N_NODES * HID;
    char* p = (char*)d_ws;
    uint2* slots  = (uint2*)p;  p += (size_t)N_EDGES * sizeof(uint2);    // 9.6 MB
    bf16*  y      = (bf16*)p;   p += N16 * sizeof(bf16);                 // 3.2 MB
    bf16*  zh     = (bf16*)p;   p += N16 * sizeof(bf16);                 // 3.2 MB (z then h)
    float* sa     = (float*)p;  p += (size_t)3 * N_NODES * sizeof(float);// 1.2 MB
    int*   deg_i  = (int*)p;    p += (size_t)N_NODES * sizeof(int);      // 0.4 MB
    int*   bcount = (int*)p;    p += NB * sizeof(int);
    int*   boff   = (int*)p;    p += (NB + 1) * sizeof(int);
    int*   cursor = (int*)p;    p += NB * sizeof(int);
    float* wc     = (float*)p;  p += 64 * sizeof(float);
    int*   flags  = (int*)p;    p += 2 * sizeof(int);
    // total ~17.65 MB (< 20 MiB ws)

    hipMemsetAsync(bcount, 0, NB * sizeof(int), stream);

    k_prep<<<1, 64, 0, stream>>>(x, ei, W1e, b1e, W1l, wc, flags);
    k_y<<<((size_t)N_NODES * 32 + 255) / 256, 256, 0, stream>>>(x, W1l, W1r, b1l, b1r,
                                                                flags, y, zh);
    k_bhist<<<256, 256, 0, stream>>>(ei, flags, bcount);
    k_bscan<<<1, 1024, 0, stream>>>(bcount, boff, cursor);
    k_bscatter<<<(N_EDGES + SC_EPB - 1) / SC_EPB, 512, 0, stream>>>(ei, flags, cursor, slots);
    k_agg1<<<NB, 512, 0, stream>>>(slots, boff, y, ea, wc, flags, zh, sa, deg_i);
    k_agg2<<<NB, 512, 0, stream>>>(slots, boff, zh, sa, deg_i, W2l, b2l, W2r, b2r,
                                   W2e, b2e, flags, d_out);
}

// Round 6
// 509.927 us; speedup vs baseline: 1.0421x; 1.0421x over previous
//
#include <hip/hip_runtime.h>
#include <hip/hip_bf16.h>
#include <stdint.h>

#define N_NODES 100000
#define N_EDGES 1200000
#define IN_CH 64
#define HID 16
#define OUT_CH 64

#define BN 50        // nodes per bucket (2000*50 == 100000 exactly)
#define NB 2000      // buckets
#define SC_EPB 8192  // edges per scatter block

typedef __hip_bfloat16 bf16;

__device__ __forceinline__ float b2f(bf16 v) { return __bfloat162float(v); }
__device__ __forceinline__ float lo_f(uint32_t p) { return __uint_as_float(p << 16); }
__device__ __forceinline__ float hi_f(uint32_t p) { return __uint_as_float(p & 0xffff0000u); }

__device__ __forceinline__ float loadf(const void* p, size_t i, int bf) {
    return bf ? b2f(((const bf16*)p)[i]) : ((const float*)p)[i];
}
__device__ __forceinline__ int loadi(const int* p, size_t i, int i64) {
    return i64 ? p[2 * i] : p[i];
}
__device__ __forceinline__ uint32_t bfbits(const void* p, size_t i, int bf) {
    if (bf) return ((const uint16_t*)p)[i];
    float v = ((const float*)p)[i];
    bf16 h = __float2bfloat16(v);
    return *reinterpret_cast<uint16_t*>(&h);
}

// Detect dtypes; fold layer-1 edge projection through W1l.
// wc[0..47] = W1e @ W1l (3x16), wc[48..63] = b1e @ W1l
__global__ void k_prep(const void* __restrict__ x, const int* __restrict__ ei,
                       const void* __restrict__ W1e, const void* __restrict__ b1e,
                       const void* __restrict__ W1l, float* __restrict__ wc,
                       int* __restrict__ flags) {
    __shared__ int s_bf;
    if (threadIdx.x == 0) {
        const uint16_t* u = (const uint16_t*)x;
        int cnt = 0;
        for (int i = 0; i < 64; ++i) {
            int e = (u[i] >> 7) & 0xff;
            cnt += (e >= 100 && e <= 140);
        }
        int bf = (cnt >= 50);
        const uint32_t* w = (const uint32_t*)ei;
        int z = 0;
        for (int i = 1; i < 64; i += 2) z += (w[i] == 0u);
        flags[0] = bf;
        flags[1] = (z >= 16);
        s_bf = bf;
    }
    __syncthreads();
    int bf = s_bf;
    int j = threadIdx.x;
    if (j >= HID) return;
    for (int r = 0; r < 3; ++r) {
        float s = 0.f;
        for (int k = 0; k < IN_CH; ++k)
            s += loadf(W1e, r * IN_CH + k, bf) * loadf(W1l, k * HID + j, bf);
        wc[r * HID + j] = s;
    }
    float s = 0.f;
    for (int k = 0; k < IN_CH; ++k)
        s += loadf(b1e, k, bf) * loadf(W1l, k * HID + j, bf);
    wc[3 * HID + j] = s;
}

// y = x@W1l -> y (bf16); z = x@W1r + b1l + b1r -> zh (bf16). 32 threads/row.
__global__ void __launch_bounds__(256) k_y(const void* __restrict__ x,
                                           const void* __restrict__ W1l,
                                           const void* __restrict__ W1r,
                                           const void* __restrict__ b1l,
                                           const void* __restrict__ b1r,
                                           const int* __restrict__ flags,
                                           bf16* __restrict__ y,
                                           bf16* __restrict__ zh) {
    __shared__ float w[IN_CH * 32];  // w[k*32+cc]: cc<16 W1l, cc>=16 W1r
    __shared__ float bz[HID];
    int bf = flags[0];
    for (int t = threadIdx.x; t < IN_CH * 32; t += 256) {
        int k = t >> 5, cc = t & 31;
        w[t] = (cc < 16) ? loadf(W1l, k * HID + cc, bf) : loadf(W1r, k * HID + (cc - 16), bf);
    }
    if (threadIdx.x < HID)
        bz[threadIdx.x] = loadf(b1l, threadIdx.x, bf) + loadf(b1r, threadIdx.x, bf);
    __syncthreads();
    int tid = blockIdx.x * 256 + threadIdx.x;
    int row = tid >> 5;
    if (row >= N_NODES) return;
    int cc = tid & 31;
    float acc = 0.f;
    if (bf) {
        const uint32_t* xr = (const uint32_t*)x + (size_t)row * (IN_CH / 2);
#pragma unroll
        for (int k2 = 0; k2 < IN_CH / 2; ++k2) {
            uint32_t p = xr[k2];
            acc += lo_f(p) * w[(2 * k2) * 32 + cc] + hi_f(p) * w[(2 * k2 + 1) * 32 + cc];
        }
    } else {
        const float* xr = (const float*)x + (size_t)row * IN_CH;
#pragma unroll
        for (int k = 0; k < IN_CH; ++k) acc += xr[k] * w[k * 32 + cc];
    }
    if (cc < 16)
        y[(size_t)row * HID + cc] = __float2bfloat16(acc);
    else
        zh[(size_t)row * HID + (cc - 16)] = __float2bfloat16(acc + bz[cc - 16]);
}

// Bucket histogram (LDS-first).
__global__ void __launch_bounds__(256) k_bhist(const int* __restrict__ ei,
                                               const int* __restrict__ flags,
                                               int* __restrict__ bcount) {
    __shared__ int lh[NB];
    for (int t = threadIdx.x; t < NB; t += 256) lh[t] = 0;
    __syncthreads();
    int i64 = flags[1];
    int stride = gridDim.x * 256;
    for (int e = blockIdx.x * 256 + threadIdx.x; e < N_EDGES; e += stride) {
        int dst = loadi(ei, (size_t)N_EDGES + e, i64);
        atomicAdd(&lh[(uint32_t)dst / BN], 1);
    }
    __syncthreads();
    for (int t = threadIdx.x; t < NB; t += 256)
        if (lh[t]) atomicAdd(&bcount[t], lh[t]);
}

// Exclusive scan of NB bucket counts -> boff[0..NB], cursor copy. 1024 thr, 2 elems each.
__global__ void __launch_bounds__(1024) k_bscan(const int* __restrict__ bcount,
                                                int* __restrict__ boff,
                                                int* __restrict__ cursor) {
    __shared__ int s[1024];
    int t = threadIdx.x;
    int i0 = 2 * t, i1 = 2 * t + 1;
    int v0 = (i0 < NB) ? bcount[i0] : 0;
    int v1 = (i1 < NB) ? bcount[i1] : 0;
    int p = v0 + v1;
    s[t] = p;
    __syncthreads();
    for (int off = 1; off < 1024; off <<= 1) {
        int v = (t >= off) ? s[t - off] : 0;
        __syncthreads();
        s[t] += v;
        __syncthreads();
    }
    int ep = s[t] - p;  // exclusive prefix of pair
    if (i0 < NB) { boff[i0] = ep; cursor[i0] = ep; }
    if (i1 < NB) { boff[i1] = ep + v0; cursor[i1] = ep + v0; }
    if (t == 1023) boff[NB] = s[1023];
}

// Counting-sort scatter: slots[.] = {src | dl<<17, ea01}, ea2v[.] = ea2 (bucket order).
__global__ void __launch_bounds__(512) k_bscatter(const int* __restrict__ ei,
                                                  const void* __restrict__ ea,
                                                  const int* __restrict__ flags,
                                                  int* __restrict__ cursor,
                                                  uint2* __restrict__ slots,
                                                  uint16_t* __restrict__ ea2v) {
    __shared__ int lhist[NB];
    __shared__ int lbase[NB];
    for (int i = threadIdx.x; i < NB; i += 512) lhist[i] = 0;
    __syncthreads();
    int i64 = flags[1], bf = flags[0];
    int base = blockIdx.x * SC_EPB;
    uint32_t bkt[16], rnk[16];
#pragma unroll
    for (int i = 0; i < 16; ++i) {
        int e = base + i * 512 + threadIdx.x;
        bkt[i] = 0xFFFFFFFFu;
        if (e < N_EDGES) {
            uint32_t d = (uint32_t)loadi(ei, (size_t)N_EDGES + e, i64);
            uint32_t b = d / BN;
            bkt[i] = b;
            rnk[i] = (uint32_t)atomicAdd(&lhist[b], 1);
        }
    }
    __syncthreads();
    for (int b = threadIdx.x; b < NB; b += 512)
        if (lhist[b]) lbase[b] = atomicAdd(&cursor[b], lhist[b]);
    __syncthreads();
#pragma unroll
    for (int i = 0; i < 16; ++i) {
        if (bkt[i] == 0xFFFFFFFFu) continue;
        int e = base + i * 512 + threadIdx.x;
        uint32_t s = (uint32_t)loadi(ei, e, i64);
        uint32_t d = (uint32_t)loadi(ei, (size_t)N_EDGES + e, i64);
        uint32_t dl = d - bkt[i] * BN;
        uint32_t ea01 = bfbits(ea, (size_t)e * 3, bf) | (bfbits(ea, (size_t)e * 3 + 1, bf) << 16);
        uint32_t ea2 = bfbits(ea, (size_t)e * 3 + 2, bf);
        size_t pos = (size_t)lbase[bkt[i]] + rnk[i];
        slots[pos] = make_uint2(s | (dl << 17), ea01);
        ea2v[pos] = (uint16_t)ea2;
    }
}

// Aggregation layer 1: persistent blocks over buckets. LDS-accumulate y[src], ea, deg;
// epilogue: h = relu(mean-path + z) in place over zh; store sa/deg.
__global__ void __launch_bounds__(512, 8) k_agg1(const uint2* __restrict__ slots,
                                                 const uint16_t* __restrict__ ea2v,
                                                 const int* __restrict__ boff,
                                                 const bf16* __restrict__ y,
                                                 const float* __restrict__ wc,
                                                 bf16* __restrict__ zh,
                                                 float* __restrict__ sa,
                                                 int* __restrict__ deg_i) {
    __shared__ float facc[BN * HID];
    __shared__ float sattr[BN * 3];
    __shared__ int sdeg[BN];
    __shared__ float swc[64];
    int t = threadIdx.x;
    if (t < 64) swc[t] = wc[t];
    int g = t >> 4, c = t & 15;
    for (int b = blockIdx.x; b < NB; b += gridDim.x) {
        for (int i = t; i < BN * HID; i += 512) facc[i] = 0.f;
        for (int i = t; i < BN * 3; i += 512) sattr[i] = 0.f;
        for (int i = t; i < BN; i += 512) sdeg[i] = 0;
        __syncthreads();
        int e0 = boff[b], e1 = boff[b + 1];
        int e = e0 + g;
        for (; e + 96 < e1; e += 128) {
            uint2 s0 = slots[e], s1 = slots[e + 32], s2 = slots[e + 64], s3 = slots[e + 96];
            float v0 = b2f(y[(s0.x & 0x1FFFFu) * HID + c]);
            float v1 = b2f(y[(s1.x & 0x1FFFFu) * HID + c]);
            float v2 = b2f(y[(s2.x & 0x1FFFFu) * HID + c]);
            float v3 = b2f(y[(s3.x & 0x1FFFFu) * HID + c]);
            int d0 = s0.x >> 17, d1 = s1.x >> 17, d2 = s2.x >> 17, d3 = s3.x >> 17;
            atomicAdd(&facc[d0 * HID + c], v0);
            atomicAdd(&facc[d1 * HID + c], v1);
            atomicAdd(&facc[d2 * HID + c], v2);
            atomicAdd(&facc[d3 * HID + c], v3);
            if (c < 2) {
                float a0 = c == 0 ? lo_f(s0.y) : hi_f(s0.y);
                float a1 = c == 0 ? lo_f(s1.y) : hi_f(s1.y);
                float a2 = c == 0 ? lo_f(s2.y) : hi_f(s2.y);
                float a3 = c == 0 ? lo_f(s3.y) : hi_f(s3.y);
                atomicAdd(&sattr[d0 * 3 + c], a0);
                atomicAdd(&sattr[d1 * 3 + c], a1);
                atomicAdd(&sattr[d2 * 3 + c], a2);
                atomicAdd(&sattr[d3 * 3 + c], a3);
            } else if (c == 2) {
                atomicAdd(&sattr[d0 * 3 + 2], __uint_as_float((uint32_t)ea2v[e] << 16));
                atomicAdd(&sattr[d1 * 3 + 2], __uint_as_float((uint32_t)ea2v[e + 32] << 16));
                atomicAdd(&sattr[d2 * 3 + 2], __uint_as_float((uint32_t)ea2v[e + 64] << 16));
                atomicAdd(&sattr[d3 * 3 + 2], __uint_as_float((uint32_t)ea2v[e + 96] << 16));
            } else if (c == 3) {
                atomicAdd(&sdeg[d0], 1);
                atomicAdd(&sdeg[d1], 1);
                atomicAdd(&sdeg[d2], 1);
                atomicAdd(&sdeg[d3], 1);
            }
        }
        for (; e < e1; e += 32) {
            uint2 s0 = slots[e];
            int d0 = s0.x >> 17;
            atomicAdd(&facc[d0 * HID + c], b2f(y[(s0.x & 0x1FFFFu) * HID + c]));
            if (c < 2)
                atomicAdd(&sattr[d0 * 3 + c], c == 0 ? lo_f(s0.y) : hi_f(s0.y));
            else if (c == 2)
                atomicAdd(&sattr[d0 * 3 + 2], __uint_as_float((uint32_t)ea2v[e] << 16));
            else if (c == 3)
                atomicAdd(&sdeg[d0], 1);
        }
        __syncthreads();
        for (int idx = t; idx < BN * HID; idx += 512) {
            int dl = idx >> 4, cc = idx & 15;
            int i = b * BN + dl;
            float d = (float)sdeg[dl];
            float inv = 1.0f / fmaxf(d, 1.0f);
            float a0 = sattr[dl * 3 + 0], a1 = sattr[dl * 3 + 1], a2 = sattr[dl * 3 + 2];
            float tt = (facc[idx] + a0 * swc[cc] + a1 * swc[16 + cc] + a2 * swc[32 + cc] +
                        d * swc[48 + cc]) * inv;
            float h = fmaxf(tt + b2f(zh[(size_t)i * HID + cc]), 0.0f);
            zh[(size_t)i * HID + cc] = __float2bfloat16(h);
            if (cc < 3) sa[i * 3 + cc] = sattr[dl * 3 + cc];
            else if (cc == 3) deg_i[i] = sdeg[dl];
        }
        __syncthreads();
    }
}

// Aggregation layer 2 + output epilogue: persistent blocks over buckets.
__global__ void __launch_bounds__(512, 8) k_agg2(const uint2* __restrict__ slots,
                                                 const int* __restrict__ boff,
                                                 const bf16* __restrict__ zh,  // holds h
                                                 const float* __restrict__ sa,
                                                 const int* __restrict__ deg_i,
                                                 const void* __restrict__ W2l,
                                                 const void* __restrict__ b2l,
                                                 const void* __restrict__ W2r,
                                                 const void* __restrict__ b2r,
                                                 const void* __restrict__ W2e,
                                                 const void* __restrict__ b2e,
                                                 const int* __restrict__ flags,
                                                 void* __restrict__ out) {
    __shared__ float facc[BN * HID];
    __shared__ float hl[BN * HID];
    __shared__ float w2l[HID * OUT_CH];
    __shared__ float w2r[HID * OUT_CH];
    __shared__ float swe[3 * HID];
    __shared__ float sbe[HID];
    __shared__ float sbb[OUT_CH];
    int t = threadIdx.x;
    int bf = flags[0];
    for (int i = t; i < HID * OUT_CH; i += 512) {
        w2l[i] = loadf(W2l, i, bf);
        w2r[i] = loadf(W2r, i, bf);
    }
    if (t < 3 * HID) swe[t] = loadf(W2e, t, bf);
    if (t < HID) sbe[t] = loadf(b2e, t, bf);
    if (t < OUT_CH) sbb[t] = loadf(b2l, t, bf) + loadf(b2r, t, bf);
    int g = t >> 4, c = t & 15;
    for (int b = blockIdx.x; b < NB; b += gridDim.x) {
        for (int i = t; i < BN * HID; i += 512) facc[i] = 0.f;
        __syncthreads();
        int e0 = boff[b], e1 = boff[b + 1];
        int e = e0 + g;
        for (; e + 96 < e1; e += 128) {
            uint2 s0 = slots[e], s1 = slots[e + 32], s2 = slots[e + 64], s3 = slots[e + 96];
            float v0 = b2f(zh[(s0.x & 0x1FFFFu) * HID + c]);
            float v1 = b2f(zh[(s1.x & 0x1FFFFu) * HID + c]);
            float v2 = b2f(zh[(s2.x & 0x1FFFFu) * HID + c]);
            float v3 = b2f(zh[(s3.x & 0x1FFFFu) * HID + c]);
            atomicAdd(&facc[(s0.x >> 17) * HID + c], v0);
            atomicAdd(&facc[(s1.x >> 17) * HID + c], v1);
            atomicAdd(&facc[(s2.x >> 17) * HID + c], v2);
            atomicAdd(&facc[(s3.x >> 17) * HID + c], v3);
        }
        for (; e < e1; e += 32) {
            uint2 s0 = slots[e];
            atomicAdd(&facc[(s0.x >> 17) * HID + c], b2f(zh[(s0.x & 0x1FFFFu) * HID + c]));
        }
        __syncthreads();
        for (int idx = t; idx < BN * HID; idx += 512) {
            int dl = idx >> 4, cc = idx & 15;
            int i = b * BN + dl;
            float d = (float)deg_i[i];
            float inv = 1.0f / fmaxf(d, 1.0f);
            float a0 = sa[i * 3 + 0], a1 = sa[i * 3 + 1], a2 = sa[i * 3 + 2];
            facc[idx] = (facc[idx] + a0 * swe[cc] + a1 * swe[16 + cc] + a2 * swe[32 + cc] +
                         d * sbe[cc]) * inv;
            hl[idx] = b2f(zh[(size_t)i * HID + cc]);
        }
        __syncthreads();
        for (int idx = t; idx < BN * OUT_CH; idx += 512) {
            int dl = idx >> 6, j = idx & 63;
            int i = b * BN + dl;
            float o = sbb[j];
#pragma unroll
            for (int cc = 0; cc < HID; ++cc)
                o += facc[dl * HID + cc] * w2l[cc * OUT_CH + j] +
                     hl[dl * HID + cc] * w2r[cc * OUT_CH + j];
            if (bf)
                ((bf16*)out)[(size_t)i * OUT_CH + j] = __float2bfloat16(o);
            else
                ((float*)out)[(size_t)i * OUT_CH + j] = o;
        }
        __syncthreads();
    }
}

extern "C" void kernel_launch(void* const* d_in, const int* in_sizes, int n_in,
                              void* d_out, int out_size, void* d_ws, size_t ws_size,
                              hipStream_t stream) {
    const void* x   = d_in[0];
    const int*  ei  = (const int*)d_in[1];
    const void* ea  = d_in[2];
    const void* W1l = d_in[3];
    const void* b1l = d_in[4];
    const void* W1r = d_in[5];
    const void* b1r = d_in[6];
    const void* W1e = d_in[7];
    const void* b1e = d_in[8];
    const void* W2l = d_in[9];
    const void* b2l = d_in[10];
    const void* W2r = d_in[11];
    const void* b2r = d_in[12];
    const void* W2e = d_in[13];
    const void* b2e = d_in[14];

    const size_t N16 = (size_t)N_NODES * HID;
    char* p = (char*)d_ws;
    uint2*    slots  = (uint2*)p;    p += (size_t)N_EDGES * sizeof(uint2);      // 9.6 MB
    uint16_t* ea2v   = (uint16_t*)p; p += (size_t)N_EDGES * sizeof(uint16_t);   // 2.4 MB
    bf16*     y      = (bf16*)p;     p += N16 * sizeof(bf16);                   // 3.2 MB
    bf16*     zh     = (bf16*)p;     p += N16 * sizeof(bf16);                   // 3.2 MB
    float*    sa     = (float*)p;    p += (size_t)3 * N_NODES * sizeof(float);  // 1.2 MB
    int*      deg_i  = (int*)p;      p += (size_t)N_NODES * sizeof(int);        // 0.4 MB
    int*      bcount = (int*)p;      p += NB * sizeof(int);
    int*      boff   = (int*)p;      p += (NB + 1) * sizeof(int);
    int*      cursor = (int*)p;      p += NB * sizeof(int);
    float*    wc     = (float*)p;    p += 64 * sizeof(float);
    int*      flags  = (int*)p;      p += 2 * sizeof(int);
    // total ~19.1 MiB

    hipMemsetAsync(bcount, 0, NB * sizeof(int), stream);

    k_prep<<<1, 64, 0, stream>>>(x, ei, W1e, b1e, W1l, wc, flags);
    k_y<<<((size_t)N_NODES * 32 + 255) / 256, 256, 0, stream>>>(x, W1l, W1r, b1l, b1r,
                                                                flags, y, zh);
    k_bhist<<<256, 256, 0, stream>>>(ei, flags, bcount);
    k_bscan<<<1, 1024, 0, stream>>>(bcount, boff, cursor);
    k_bscatter<<<(N_EDGES + SC_EPB - 1) / SC_EPB, 512, 0, stream>>>(ei, ea, flags, cursor,
                                                                    slots, ea2v);
    k_agg1<<<1024, 512, 0, stream>>>(slots, ea2v, boff, y, wc, zh, sa, deg_i);
    k_agg2<<<1024, 512, 0, stream>>>(slots, boff, zh, sa, deg_i, W2l, b2l, W2r, b2r,
                                     W2e, b2e, flags, d_out);
}